// Round 5
// baseline (209.586 us; speedup 1.0000x reference)
//
#include <hip/hip_runtime.h>

#define D 256
#define F4_PER_ROW (D / 4)  // 64 float4 per row

typedef float fx4 __attribute__((ext_vector_type(4)));  // native vec for nontemporal builtin

__device__ __forceinline__ float dot4(float4 a, float4 b) {
    return fmaf(a.x, b.x, fmaf(a.y, b.y, fmaf(a.z, b.z, a.w * b.w)));
}

__device__ __forceinline__ void nt_store4(float4 v, float4* p) {
    fx4 t; t.x = v.x; t.y = v.y; t.z = v.z; t.w = v.w;
    __builtin_nontemporal_store(t, reinterpret_cast<fx4*>(p));
}

// 2 rows per wave (32 lanes/row, 8 floats/lane/input), grid-stride over
// 2-row units with register double-buffer prefetch: next iteration's 8
// loads are issued BEFORE the current iteration's reduction, so every
// wave keeps ~8KB in flight during compute (latency hiding).
__global__ __launch_bounds__(256) void merge_xs_kernel(
    const float* __restrict__ x0, const float* __restrict__ x1,
    const float* __restrict__ x2, const float* __restrict__ x3,
    const float* __restrict__ w_att, const float* __restrict__ b_att,
    float* __restrict__ emb, float* __restrict__ sc_out, int N)
{
    const int lane = threadIdx.x & 63;
    const int sub  = lane & 31;       // lane within the row's 32-lane group
    const int half = lane >> 5;       // which of the wave's 2 rows
    const int wid  = threadIdx.x >> 6;
    const int wpb  = blockDim.x >> 6;
    const int nwaves = gridDim.x * wpb;

    const int nUnits = (N + 1) >> 1;
    int unit = blockIdx.x * wpb + wid;
    if (unit >= nUnits) return;

    const float4* x0f = reinterpret_cast<const float4*>(x0);
    const float4* x1f = reinterpret_cast<const float4*>(x1);
    const float4* x2f = reinterpret_cast<const float4*>(x2);
    const float4* x3f = reinterpret_cast<const float4*>(x3);
    float4* embf      = reinterpret_cast<float4*>(emb);

    // Weight slices (L1/L2-resident), hoisted.
    const float4* wmf = reinterpret_cast<const float4*>(w_att);  // w_att[0:256]
    const float4* wqf = wmf + 64;                                // w_att[256:512]
    const float4 wma = wmf[sub], wmb = wmf[sub + 32];
    const float4 wqa = wqf[sub], wqb = wqf[sub + 32];
    const float b = b_att[0];

    // Current-iteration registers.
    size_t base = (size_t)(unit * 2 + half) * F4_PER_ROW + sub;
    float4 v0a = x0f[base], v0b = x0f[base + 32];
    float4 v1a = x1f[base], v1b = x1f[base + 32];
    float4 v2a = x2f[base], v2b = x2f[base + 32];
    float4 v3a = x3f[base], v3b = x3f[base + 32];

    for (;;) {
        const int next = unit + nwaves;
        const bool has_next = next < nUnits;   // wave-uniform

        // Prefetch next unit's inputs (issued before the long reduction).
        float4 p0a, p0b, p1a, p1b, p2a, p2b, p3a, p3b;
        size_t nbase = 0;
        if (has_next) {
            nbase = (size_t)(next * 2 + half) * F4_PER_ROW + sub;
            p0a = x0f[nbase]; p0b = x0f[nbase + 32];
            p1a = x1f[nbase]; p1b = x1f[nbase + 32];
            p2a = x2f[nbase]; p2b = x2f[nbase + 32];
            p3a = x3f[nbase]; p3b = x3f[nbase + 32];
        }

        // 8 per-lane partials: ||x||^2 and weight-dot for each input.
        float r0 = dot4(v0a, v0a) + dot4(v0b, v0b);
        float r1 = dot4(v0a, wqa) + dot4(v0b, wqb);
        float r2 = dot4(v1a, v1a) + dot4(v1b, v1b);
        float r3 = dot4(v1a, wma) + dot4(v1b, wmb);
        float r4 = dot4(v2a, v2a) + dot4(v2b, v2b);
        float r5 = dot4(v2a, wma) + dot4(v2b, wmb);
        float r6 = dot4(v3a, v3a) + dot4(v3b, v3b);
        float r7 = dot4(v3a, wma) + dot4(v3b, wmb);

        // Butterfly over 32 lanes (offsets < 32 stay within each half-wave).
        #pragma unroll
        for (int off = 16; off > 0; off >>= 1) {
            r0 += __shfl_xor(r0, off, 64);
            r1 += __shfl_xor(r1, off, 64);
            r2 += __shfl_xor(r2, off, 64);
            r3 += __shfl_xor(r3, off, 64);
            r4 += __shfl_xor(r4, off, 64);
            r5 += __shfl_xor(r5, off, 64);
            r6 += __shfl_xor(r6, off, 64);
            r7 += __shfl_xor(r7, off, 64);
        }

        const float n0 = fmaxf(sqrtf(r0), 1e-12f);
        const float n1 = fmaxf(sqrtf(r2), 1e-12f);
        const float n2 = fmaxf(sqrtf(r4), 1e-12f);
        const float n3 = fmaxf(sqrtf(r6), 1e-12f);

        const float qterm = r1 / n0 + b;
        float s1 = r3 / n1 + qterm;
        float s2 = r5 / n2 + qterm;
        float s3 = r7 / n3 + qterm;

        // leaky_relu(0.01)
        s1 = s1 > 0.f ? s1 : 0.01f * s1;
        s2 = s2 > 0.f ? s2 : 0.01f * s2;
        s3 = s3 > 0.f ? s3 : 0.01f * s3;

        // softmax over the 3 messages
        const float m  = fmaxf(s1, fmaxf(s2, s3));
        const float e1 = expf(s1 - m);
        const float e2 = expf(s2 - m);
        const float e3 = expf(s3 - m);
        const float inv = 1.0f / (e1 + e2 + e3);
        const float sc1 = e1 * inv, sc2 = e2 * inv, sc3 = e3 * inv;

        // embedding = x0 + sum_l (sc_l / ||x_l||) * x_l
        const float c1 = sc1 / n1, c2 = sc2 / n2, c3 = sc3 / n3;
        float4 oa, ob;
        oa.x = fmaf(c1, v1a.x, fmaf(c2, v2a.x, fmaf(c3, v3a.x, v0a.x)));
        oa.y = fmaf(c1, v1a.y, fmaf(c2, v2a.y, fmaf(c3, v3a.y, v0a.y)));
        oa.z = fmaf(c1, v1a.z, fmaf(c2, v2a.z, fmaf(c3, v3a.z, v0a.z)));
        oa.w = fmaf(c1, v1a.w, fmaf(c2, v2a.w, fmaf(c3, v3a.w, v0a.w)));
        ob.x = fmaf(c1, v1b.x, fmaf(c2, v2b.x, fmaf(c3, v3b.x, v0b.x)));
        ob.y = fmaf(c1, v1b.y, fmaf(c2, v2b.y, fmaf(c3, v3b.y, v0b.y)));
        ob.z = fmaf(c1, v1b.z, fmaf(c2, v2b.z, fmaf(c3, v3b.z, v0b.z)));
        ob.w = fmaf(c1, v1b.w, fmaf(c2, v2b.w, fmaf(c3, v3b.w, v0b.w)));

        const int row = unit * 2 + half;
        if (row < N) {
            nt_store4(oa, &embf[base]);
            nt_store4(ob, &embf[base + 32]);
            if (sub == 0) {
                __builtin_nontemporal_store(sc1, &sc_out[row]);
                __builtin_nontemporal_store(sc2, &sc_out[N + row]);
                __builtin_nontemporal_store(sc3, &sc_out[2 * N + row]);
            }
        }

        if (!has_next) break;
        // Rotate prefetched registers in.
        v0a = p0a; v0b = p0b; v1a = p1a; v1b = p1b;
        v2a = p2a; v2b = p2b; v3a = p3a; v3b = p3b;
        base = nbase;
        unit = next;
    }
}

extern "C" void kernel_launch(void* const* d_in, const int* in_sizes, int n_in,
                              void* d_out, int out_size, void* d_ws, size_t ws_size,
                              hipStream_t stream) {
    const float* x0    = (const float*)d_in[0];
    const float* x1    = (const float*)d_in[1];
    const float* x2    = (const float*)d_in[2];
    const float* x3    = (const float*)d_in[3];
    const float* w_att = (const float*)d_in[4];
    const float* b_att = (const float*)d_in[5];

    const int N = in_sizes[0] / D;  // 200000
    float* emb = (float*)d_out;
    float* sc  = emb + (size_t)N * D;

    const int threads = 256;                 // 4 waves/block, 2 rows/wave
    const int wpb = threads / 64;
    const int nUnits = (N + 1) / 2;          // 100000
    // ~8 units per wave, exact division for N=200000 -> zero tail imbalance.
    const int ITERS = 8;
    int nwaves = (nUnits + ITERS - 1) / ITERS;           // 12500
    int blocks = (nwaves + wpb - 1) / wpb;               // 3125
    merge_xs_kernel<<<blocks, threads, 0, stream>>>(x0, x1, x2, x3, w_att, b_att,
                                                    emb, sc, N);
}

// Round 6
// 196.054 us; speedup vs baseline: 1.0690x; 1.0690x over previous
//
#include <hip/hip_runtime.h>

#define D 256
#define F4_PER_ROW (D / 4)  // 64 float4 per row

typedef float fx4 __attribute__((ext_vector_type(4)));  // native vec for nontemporal builtin

__device__ __forceinline__ float dot4(float4 a, float4 b) {
    return fmaf(a.x, b.x, fmaf(a.y, b.y, fmaf(a.z, b.z, a.w * b.w)));
}

__device__ __forceinline__ void nt_store4(float4 v, float4* p) {
    fx4 t; t.x = v.x; t.y = v.y; t.z = v.z; t.w = v.w;
    __builtin_nontemporal_store(t, reinterpret_cast<fx4*>(p));
}

// 2 rows per wave (32 lanes/row), 4 units per wave, register double-buffer.
// Prefetch loads are UNCONDITIONAL (clamped index) and pinned with
// sched_barrier(0) so they issue before the dependent reduction — each wave
// keeps 8KB in flight during its whole compute phase (duty-cycle fix).
__global__ __launch_bounds__(256) void merge_xs_kernel(
    const float* __restrict__ x0, const float* __restrict__ x1,
    const float* __restrict__ x2, const float* __restrict__ x3,
    const float* __restrict__ w_att, const float* __restrict__ b_att,
    float* __restrict__ emb, float* __restrict__ sc_out, int N)
{
    const int lane = threadIdx.x & 63;
    const int sub  = lane & 31;       // lane within the row's 32-lane group
    const int half = lane >> 5;       // which of the wave's 2 rows
    const int wid  = threadIdx.x >> 6;
    const int wpb  = blockDim.x >> 6;
    const int nwaves = gridDim.x * wpb;

    const int nUnits = (N + 1) >> 1;
    int unit = blockIdx.x * wpb + wid;
    if (unit >= nUnits) return;

    const float4* x0f = reinterpret_cast<const float4*>(x0);
    const float4* x1f = reinterpret_cast<const float4*>(x1);
    const float4* x2f = reinterpret_cast<const float4*>(x2);
    const float4* x3f = reinterpret_cast<const float4*>(x3);
    float4* embf      = reinterpret_cast<float4*>(emb);

    // Weight slices (L1/L2-resident), hoisted.
    const float4* wmf = reinterpret_cast<const float4*>(w_att);  // w_att[0:256]
    const float4* wqf = wmf + 64;                                // w_att[256:512]
    const float4 wma = wmf[sub], wmb = wmf[sub + 32];
    const float4 wqa = wqf[sub], wqb = wqf[sub + 32];
    const float b = b_att[0];

    // Current-iteration registers.
    size_t base = (size_t)(unit * 2 + half) * F4_PER_ROW + sub;
    float4 v0a = x0f[base], v0b = x0f[base + 32];
    float4 v1a = x1f[base], v1b = x1f[base + 32];
    float4 v2a = x2f[base], v2b = x2f[base + 32];
    float4 v3a = x3f[base], v3b = x3f[base + 32];

    for (;;) {
        const int next = unit + nwaves;
        // Clamped, UNCONDITIONAL prefetch — compiler cannot predicate it away.
        const int nclamp = next < nUnits ? next : unit;
        const size_t nbase = (size_t)(nclamp * 2 + half) * F4_PER_ROW + sub;
        float4 p0a = x0f[nbase], p0b = x0f[nbase + 32];
        float4 p1a = x1f[nbase], p1b = x1f[nbase + 32];
        float4 p2a = x2f[nbase], p2b = x2f[nbase + 32];
        float4 p3a = x3f[nbase], p3b = x3f[nbase + 32];
        // Pin the prefetch: no instruction may be hoisted above/sunk below here.
        __builtin_amdgcn_sched_barrier(0);

        // 8 per-lane partials: ||x||^2 and weight-dot for each input.
        float r0 = dot4(v0a, v0a) + dot4(v0b, v0b);
        float r1 = dot4(v0a, wqa) + dot4(v0b, wqb);
        float r2 = dot4(v1a, v1a) + dot4(v1b, v1b);
        float r3 = dot4(v1a, wma) + dot4(v1b, wmb);
        float r4 = dot4(v2a, v2a) + dot4(v2b, v2b);
        float r5 = dot4(v2a, wma) + dot4(v2b, wmb);
        float r6 = dot4(v3a, v3a) + dot4(v3b, v3b);
        float r7 = dot4(v3a, wma) + dot4(v3b, wmb);

        // Butterfly over 32 lanes (offsets < 32 stay within each half-wave).
        #pragma unroll
        for (int off = 16; off > 0; off >>= 1) {
            r0 += __shfl_xor(r0, off, 64);
            r1 += __shfl_xor(r1, off, 64);
            r2 += __shfl_xor(r2, off, 64);
            r3 += __shfl_xor(r3, off, 64);
            r4 += __shfl_xor(r4, off, 64);
            r5 += __shfl_xor(r5, off, 64);
            r6 += __shfl_xor(r6, off, 64);
            r7 += __shfl_xor(r7, off, 64);
        }

        const float n0 = fmaxf(sqrtf(r0), 1e-12f);
        const float n1 = fmaxf(sqrtf(r2), 1e-12f);
        const float n2 = fmaxf(sqrtf(r4), 1e-12f);
        const float n3 = fmaxf(sqrtf(r6), 1e-12f);

        const float qterm = r1 / n0 + b;
        float s1 = r3 / n1 + qterm;
        float s2 = r5 / n2 + qterm;
        float s3 = r7 / n3 + qterm;

        // leaky_relu(0.01)
        s1 = s1 > 0.f ? s1 : 0.01f * s1;
        s2 = s2 > 0.f ? s2 : 0.01f * s2;
        s3 = s3 > 0.f ? s3 : 0.01f * s3;

        // softmax over the 3 messages
        const float m  = fmaxf(s1, fmaxf(s2, s3));
        const float e1 = expf(s1 - m);
        const float e2 = expf(s2 - m);
        const float e3 = expf(s3 - m);
        const float inv = 1.0f / (e1 + e2 + e3);
        const float sc1 = e1 * inv, sc2 = e2 * inv, sc3 = e3 * inv;

        // embedding = x0 + sum_l (sc_l / ||x_l||) * x_l
        const float c1 = sc1 / n1, c2 = sc2 / n2, c3 = sc3 / n3;
        float4 oa, ob;
        oa.x = fmaf(c1, v1a.x, fmaf(c2, v2a.x, fmaf(c3, v3a.x, v0a.x)));
        oa.y = fmaf(c1, v1a.y, fmaf(c2, v2a.y, fmaf(c3, v3a.y, v0a.y)));
        oa.z = fmaf(c1, v1a.z, fmaf(c2, v2a.z, fmaf(c3, v3a.z, v0a.z)));
        oa.w = fmaf(c1, v1a.w, fmaf(c2, v2a.w, fmaf(c3, v3a.w, v0a.w)));
        ob.x = fmaf(c1, v1b.x, fmaf(c2, v2b.x, fmaf(c3, v3b.x, v0b.x)));
        ob.y = fmaf(c1, v1b.y, fmaf(c2, v2b.y, fmaf(c3, v3b.y, v0b.y)));
        ob.z = fmaf(c1, v1b.z, fmaf(c2, v2b.z, fmaf(c3, v3b.z, v0b.z)));
        ob.w = fmaf(c1, v1b.w, fmaf(c2, v2b.w, fmaf(c3, v3b.w, v0b.w)));

        const int row = unit * 2 + half;
        if (row < N) {
            nt_store4(oa, &embf[base]);
            nt_store4(ob, &embf[base + 32]);
            if (sub == 0) {
                __builtin_nontemporal_store(sc1, &sc_out[row]);
                __builtin_nontemporal_store(sc2, &sc_out[N + row]);
                __builtin_nontemporal_store(sc3, &sc_out[2 * N + row]);
            }
        }

        if (next >= nUnits) break;
        // Rotate prefetched registers in.
        v0a = p0a; v0b = p0b; v1a = p1a; v1b = p1b;
        v2a = p2a; v2b = p2b; v3a = p3a; v3b = p3b;
        base = nbase;
        unit = next;
    }
}

extern "C" void kernel_launch(void* const* d_in, const int* in_sizes, int n_in,
                              void* d_out, int out_size, void* d_ws, size_t ws_size,
                              hipStream_t stream) {
    const float* x0    = (const float*)d_in[0];
    const float* x1    = (const float*)d_in[1];
    const float* x2    = (const float*)d_in[2];
    const float* x3    = (const float*)d_in[3];
    const float* w_att = (const float*)d_in[4];
    const float* b_att = (const float*)d_in[5];

    const int N = in_sizes[0] / D;  // 200000
    float* emb = (float*)d_out;
    float* sc  = emb + (size_t)N * D;

    const int threads = 256;                 // 4 waves/block, 2 rows/wave
    const int wpb = threads / 64;
    const int nUnits = (N + 1) / 2;          // 100000
    // Exactly 4 units per wave for N=200000 (100000/25000) -> zero tail imbalance,
    // ~5 block-generations per CU for natural phase stagger.
    const int ITERS = 4;
    int nwaves = (nUnits + ITERS - 1) / ITERS;   // 25000
    int blocks = (nwaves + wpb - 1) / wpb;       // 6250
    merge_xs_kernel<<<blocks, threads, 0, stream>>>(x0, x1, x2, x3, w_att, b_att,
                                                    emb, sc, N);
}

// Round 8
// 188.049 us; speedup vs baseline: 1.1145x; 1.0426x over previous
//
#include <hip/hip_runtime.h>

#define D 256
#define F4_PER_ROW (D / 4)  // 64 float4 per row

typedef float fx4 __attribute__((ext_vector_type(4)));  // native vec for nontemporal builtin

__device__ __forceinline__ float dot4(float4 a, float4 b) {
    return fmaf(a.x, b.x, fmaf(a.y, b.y, fmaf(a.z, b.z, a.w * b.w)));
}

__device__ __forceinline__ void nt_store4(float4 v, float4* p) {
    fx4 t; t.x = v.x; t.y = v.y; t.z = v.z; t.w = v.w;
    __builtin_nontemporal_store(t, reinterpret_cast<fx4*>(p));
}

// One 2-row unit per wave (32 lanes/row, 8 floats/lane/input), one-shot —
// TLP from 100k waves hides latency. Epilogue uses native rsq/rcp/exp2 to
// minimize the serial lane-redundant tail (wave lifetime -> wave throughput).
__global__ __launch_bounds__(1024) void merge_xs_kernel(
    const float* __restrict__ x0, const float* __restrict__ x1,
    const float* __restrict__ x2, const float* __restrict__ x3,
    const float* __restrict__ w_att, const float* __restrict__ b_att,
    float* __restrict__ emb, float* __restrict__ sc_out, int N)
{
    const int lane = threadIdx.x & 63;
    const int sub  = lane & 31;       // lane within the row's 32-lane group
    const int half = lane >> 5;       // which of the wave's 2 rows
    const int wid  = threadIdx.x >> 6;
    const int wpb  = blockDim.x >> 6;

    const int nUnits = (N + 1) >> 1;
    const int unit = blockIdx.x * wpb + wid;
    if (unit >= nUnits) return;

    const int row = unit * 2 + half;
    const bool valid = row < N;
    const size_t base = valid ? ((size_t)row * F4_PER_ROW + sub) : (size_t)sub;

    const float4* x0f = reinterpret_cast<const float4*>(x0);
    const float4* x1f = reinterpret_cast<const float4*>(x1);
    const float4* x2f = reinterpret_cast<const float4*>(x2);
    const float4* x3f = reinterpret_cast<const float4*>(x3);
    float4* embf      = reinterpret_cast<float4*>(emb);

    // Input loads first — get them in flight immediately.
    float4 v0a = x0f[base], v0b = x0f[base + 32];
    float4 v1a = x1f[base], v1b = x1f[base + 32];
    float4 v2a = x2f[base], v2b = x2f[base + 32];
    float4 v3a = x3f[base], v3b = x3f[base + 32];

    // Weight slices (L1/L2-resident).
    const float4* wmf = reinterpret_cast<const float4*>(w_att);  // w_att[0:256]
    const float4* wqf = wmf + 64;                                // w_att[256:512]
    const float4 wma = wmf[sub], wmb = wmf[sub + 32];
    const float4 wqa = wqf[sub], wqb = wqf[sub + 32];
    const float b = b_att[0];

    // 8 per-lane partials: ||x||^2 and weight-dot for each input.
    float r0 = dot4(v0a, v0a) + dot4(v0b, v0b);
    float r1 = dot4(v0a, wqa) + dot4(v0b, wqb);
    float r2 = dot4(v1a, v1a) + dot4(v1b, v1b);
    float r3 = dot4(v1a, wma) + dot4(v1b, wmb);
    float r4 = dot4(v2a, v2a) + dot4(v2b, v2b);
    float r5 = dot4(v2a, wma) + dot4(v2b, wmb);
    float r6 = dot4(v3a, v3a) + dot4(v3b, v3b);
    float r7 = dot4(v3a, wma) + dot4(v3b, wmb);

    // Butterfly over 32 lanes (offsets < 32 stay within each half-wave).
    #pragma unroll
    for (int off = 16; off > 0; off >>= 1) {
        r0 += __shfl_xor(r0, off, 64);
        r1 += __shfl_xor(r1, off, 64);
        r2 += __shfl_xor(r2, off, 64);
        r3 += __shfl_xor(r3, off, 64);
        r4 += __shfl_xor(r4, off, 64);
        r5 += __shfl_xor(r5, off, 64);
        r6 += __shfl_xor(r6, off, 64);
        r7 += __shfl_xor(r7, off, 64);
    }

    // 1/||x|| directly via v_rsq_f32 (clamp matches eps=1e-12 on the norm).
    const float in0 = __builtin_amdgcn_rsqf(fmaxf(r0, 1e-24f));
    const float in1 = __builtin_amdgcn_rsqf(fmaxf(r2, 1e-24f));
    const float in2 = __builtin_amdgcn_rsqf(fmaxf(r4, 1e-24f));
    const float in3 = __builtin_amdgcn_rsqf(fmaxf(r6, 1e-24f));

    const float qterm = fmaf(r1, in0, b);
    float s1 = fmaf(r3, in1, qterm);
    float s2 = fmaf(r5, in2, qterm);
    float s3 = fmaf(r7, in3, qterm);

    // leaky_relu(0.01)
    s1 = s1 > 0.f ? s1 : 0.01f * s1;
    s2 = s2 > 0.f ? s2 : 0.01f * s2;
    s3 = s3 > 0.f ? s3 : 0.01f * s3;

    // softmax over the 3 messages — native exp2/rcp.
    const float m  = fmaxf(s1, fmaxf(s2, s3));
    const float LOG2E = 1.4426950408889634f;
    const float e1 = __builtin_amdgcn_exp2f((s1 - m) * LOG2E);
    const float e2 = __builtin_amdgcn_exp2f((s2 - m) * LOG2E);
    const float e3 = __builtin_amdgcn_exp2f((s3 - m) * LOG2E);
    const float inv = __builtin_amdgcn_rcpf(e1 + e2 + e3);
    const float sc1 = e1 * inv, sc2 = e2 * inv, sc3 = e3 * inv;

    // embedding = x0 + sum_l (sc_l / ||x_l||) * x_l
    const float c1 = sc1 * in1, c2 = sc2 * in2, c3 = sc3 * in3;
    float4 oa, ob;
    oa.x = fmaf(c1, v1a.x, fmaf(c2, v2a.x, fmaf(c3, v3a.x, v0a.x)));
    oa.y = fmaf(c1, v1a.y, fmaf(c2, v2a.y, fmaf(c3, v3a.y, v0a.y)));
    oa.z = fmaf(c1, v1a.z, fmaf(c2, v2a.z, fmaf(c3, v3a.z, v0a.z)));
    oa.w = fmaf(c1, v1a.w, fmaf(c2, v2a.w, fmaf(c3, v3a.w, v0a.w)));
    ob.x = fmaf(c1, v1b.x, fmaf(c2, v2b.x, fmaf(c3, v3b.x, v0b.x)));
    ob.y = fmaf(c1, v1b.y, fmaf(c2, v2b.y, fmaf(c3, v3b.y, v0b.y)));
    ob.z = fmaf(c1, v1b.z, fmaf(c2, v2b.z, fmaf(c3, v3b.z, v0b.z)));
    ob.w = fmaf(c1, v1b.w, fmaf(c2, v2b.w, fmaf(c3, v3b.w, v0b.w)));

    if (valid) {
        nt_store4(oa, &embf[base]);
        nt_store4(ob, &embf[base + 32]);
        if (sub == 0) {
            __builtin_nontemporal_store(sc1, &sc_out[row]);
            __builtin_nontemporal_store(sc2, &sc_out[N + row]);
            __builtin_nontemporal_store(sc3, &sc_out[2 * N + row]);
        }
    }
}

extern "C" void kernel_launch(void* const* d_in, const int* in_sizes, int n_in,
                              void* d_out, int out_size, void* d_ws, size_t ws_size,
                              hipStream_t stream) {
    const float* x0    = (const float*)d_in[0];
    const float* x1    = (const float*)d_in[1];
    const float* x2    = (const float*)d_in[2];
    const float* x3    = (const float*)d_in[3];
    const float* w_att = (const float*)d_in[4];
    const float* b_att = (const float*)d_in[5];

    const int N = in_sizes[0] / D;  // 200000
    float* emb = (float*)d_out;
    float* sc  = emb + (size_t)N * D;

    const int threads = 1024;               // 16 waves/block, 2 rows/wave
    const int wpb = threads / 64;
    const int nUnits = (N + 1) / 2;         // 100000
    const int blocks = (nUnits + wpb - 1) / wpb;  // 6250 — one unit per wave

    merge_xs_kernel<<<blocks, threads, 0, stream>>>(x0, x1, x2, x3, w_att, b_att,
                                                    emb, sc, N);
}